// Round 7
// baseline (43.532 us; speedup 1.0000x reference)
//
#include <hip/hip_runtime.h>

typedef __attribute__((ext_vector_type(8))) short short8;
typedef __attribute__((ext_vector_type(4))) float f32x4;

static __device__ inline unsigned short f2bf(float x) {
    unsigned int u = __float_as_uint(x);
    u = (u + 0x7FFFu + ((u >> 16) & 1u)) >> 16;
    return (unsigned short)u;
}

// ---------------- Kernel 1: L2-normalize rows, cast to bf16 ----------------
__global__ __launch_bounds__(256) void knorm(const float* __restrict__ feats,
                                             const float* __restrict__ nfeats,
                                             unsigned short* __restrict__ fb,
                                             unsigned short* __restrict__ gb) {
    int row = blockIdx.x * 4 + (threadIdx.x >> 6);
    int lane = threadIdx.x & 63;
    const float* src;
    unsigned short* dst;
    if (row < 4096) { src = feats + row * 128;           dst = fb + row * 128; }
    else            { src = nfeats + (row - 4096) * 128; dst = gb + (row - 4096) * 128; }
    float2 v = ((const float2*)src)[lane];
    float ss = v.x * v.x + v.y * v.y;
    #pragma unroll
    for (int d = 32; d; d >>= 1) ss += __shfl_xor(ss, d);
    float inv = 1.0f / sqrtf(ss);
    ushort2 o;
    o.x = f2bf(v.x * inv);
    o.y = f2bf(v.y * inv);
    ((ushort2*)dst)[lane] = o;
}

// ---------------- Kernel 2: partial max_q dot(f[p], g[q]) via MFMA ----------
// NO LDS, NO barriers: g is L2-resident (1.25 MB/XCD with m-pinning), so B
// fragments load straight from global.  grid (8 m, 64 = n*16+pg, 2 qhh),
// 256 thr = 4 free-running waves.  Wave = 64 p-rows x 128 q-rows (qs = bz*4+w),
// B-frag reused 4x in regs; 8 q-tiles x {4 b-loads + 16 MFMA in 4 indep chains}.
// grid.x = m = 8 pins each m's gb slice to one XCD (linear%8 round-robin).
__global__ __launch_bounds__(256, 3) void kscore(const unsigned short* __restrict__ fb,
                                                 const unsigned short* __restrict__ gb,
                                                 float* __restrict__ sp_part) {
    const int tid = threadIdx.x;
    const int lane = tid & 63;
    const int w = tid >> 6;                 // 0..3
    const int l15 = lane & 15, lhi = lane >> 4;
    const int m = blockIdx.x;
    const int n = blockIdx.y >> 4, pgb = blockIdx.y & 15;
    const int qs = blockIdx.z * 4 + w;      // 0..7 q-slice of 128 rows
    const int p0 = pgb * 64;

    // A fragments: 4 p-groups x 4 k-groups (64 VGPR), persistent
    short8 a[4][4];
    #pragma unroll
    for (int pg = 0; pg < 4; pg++) {
        const unsigned short* arow = fb + (size_t)(n * 1024 + p0 + pg * 16 + l15) * 128;
        #pragma unroll
        for (int kk = 0; kk < 4; kk++)
            a[pg][kk] = *(const short8*)(arow + kk * 32 + lhi * 8);
    }

    const unsigned short* gBase = gb + ((size_t)m * 1024 + qs * 128) * 128 + lhi * 8;

    f32x4 mx[4];
    #pragma unroll
    for (int pg = 0; pg < 4; pg++)
        #pragma unroll
        for (int i = 0; i < 4; i++) mx[pg][i] = -1e30f;

    #pragma unroll
    for (int qt = 0; qt < 8; qt++) {
        const unsigned short* grow = gBase + (size_t)(qt * 16 + l15) * 128;
        short8 b0 = *(const short8*)(grow);
        short8 b1 = *(const short8*)(grow + 32);
        short8 b2 = *(const short8*)(grow + 64);
        short8 b3 = *(const short8*)(grow + 96);
        f32x4 acc[4];
        #pragma unroll
        for (int pg = 0; pg < 4; pg++) {
            #pragma unroll
            for (int i = 0; i < 4; i++) acc[pg][i] = 0.f;
            acc[pg] = __builtin_amdgcn_mfma_f32_16x16x32_bf16(a[pg][0], b0, acc[pg], 0, 0, 0);
            acc[pg] = __builtin_amdgcn_mfma_f32_16x16x32_bf16(a[pg][1], b1, acc[pg], 0, 0, 0);
            acc[pg] = __builtin_amdgcn_mfma_f32_16x16x32_bf16(a[pg][2], b2, acc[pg], 0, 0, 0);
            acc[pg] = __builtin_amdgcn_mfma_f32_16x16x32_bf16(a[pg][3], b3, acc[pg], 0, 0, 0);
        }
        #pragma unroll
        for (int pg = 0; pg < 4; pg++)
            #pragma unroll
            for (int i = 0; i < 4; i++) mx[pg][i] = fmaxf(mx[pg][i], acc[pg][i]);
    }

    // reduce max over the 16 q-columns (C/D col = lane&15)
    #pragma unroll
    for (int pg = 0; pg < 4; pg++)
        #pragma unroll
        for (int i = 0; i < 4; i++) {
            float v = mx[pg][i];
            v = fmaxf(v, __shfl_xor(v, 1));
            v = fmaxf(v, __shfl_xor(v, 2));
            v = fmaxf(v, __shfl_xor(v, 4));
            v = fmaxf(v, __shfl_xor(v, 8));
            mx[pg][i] = v;
        }
    if (l15 == 0) {
        #pragma unroll
        for (int pg = 0; pg < 4; pg++)
            #pragma unroll
            for (int i = 0; i < 4; i++) {
                int p = p0 + pg * 16 + lhi * 4 + i;
                sp_part[((size_t)(n * 8 + m) * 8 + qs) * 1024 + p] = mx[pg][i];
            }
    }
}

// --------- Kernel 3: fused fold + scores + bilinear upsample ---------------
// grid (65, 4): bx<64 -> 8-row output band; bx==64 -> scores[n]
__global__ __launch_bounds__(256) void kfinal(const float* __restrict__ sp_part,
                                              const float* __restrict__ mask,
                                              float* __restrict__ out) {
    const int n = blockIdx.y;
    const int bx = blockIdx.x;
    const int t = threadIdx.x;
    float* pix = out + 4;

    if (bx == 64) {  // ---- scores[n] = mean_m max_p dist ----
        __shared__ float smax[4];
        float acc = 0.f;
        for (int m = 0; m < 8; m++) {
            const float* base = sp_part + (size_t)(n * 8 + m) * 8 * 1024;
            float lm = -1e30f;
            #pragma unroll
            for (int i = 0; i < 4; i++) {
                int p = i * 256 + t;
                float dot = -1e30f;
                #pragma unroll
                for (int s = 0; s < 8; s++) dot = fmaxf(dot, base[s * 1024 + p]);
                float d = sqrtf(fmaxf(2.0f - 2.0f * dot, 0.0f)) * 0.5f * mask[n * 1024 + p];
                lm = fmaxf(lm, d);
            }
            #pragma unroll
            for (int d = 32; d; d >>= 1) lm = fmaxf(lm, __shfl_xor(lm, d));
            if ((t & 63) == 0) smax[t >> 6] = lm;
            __syncthreads();
            if (t == 0) acc += fmaxf(fmaxf(smax[0], smax[1]), fmaxf(smax[2], smax[3]));
            __syncthreads();
        }
        if (t == 0) out[n] = acc * 0.125f;
        return;
    }

    // ---- output band: rows [bx*8, bx*8+8); needs 2 consecutive patch rows ----
    __shared__ float sp_row[2][32];
    const int band = bx * 8;
    const int pr_lo = (int)floorf((band + 0.5f) * 0.0625f - 0.5f);
    const int row0 = min(max(pr_lo, 0), 31);
    const int row1 = min(max(pr_lo + 1, 0), 31);
    {
        int v = t >> 2, sub = t & 3;          // 64 values x 4 threads
        int vr = v >> 5, vc = v & 31;
        int p = (vr ? row1 : row0) * 32 + vc;
        float sum = 0.f;
        #pragma unroll
        for (int mi = 0; mi < 2; mi++) {
            int m = sub * 2 + mi;
            const float* base = sp_part + (size_t)(n * 8 + m) * 8 * 1024 + p;
            float dot = -1e30f;
            #pragma unroll
            for (int s = 0; s < 8; s++) dot = fmaxf(dot, base[s * 1024]);
            sum += sqrtf(fmaxf(2.0f - 2.0f * dot, 0.0f)) * 0.5f;
        }
        sum *= mask[n * 1024 + p];
        sum += __shfl_xor(sum, 1);
        sum += __shfl_xor(sum, 2);
        if (sub == 0) sp_row[vr][vc] = sum * 0.125f;
    }
    __syncthreads();
    #pragma unroll
    for (int i = 0; i < 16; i++) {
        int idx = i * 256 + t;
        int yl = idx >> 9, x = idx & 511;
        int y = band + yl;
        float fy = (y + 0.5f) * 0.0625f - 0.5f;
        float ty = fy - (float)pr_lo;          // rows {pr_lo, pr_lo+1}; clamped dup at edges
        float fx = (x + 0.5f) * 0.0625f - 0.5f;
        float xf = floorf(fx);
        float tx = fx - xf;
        int x0 = (int)xf;
        int x0c = min(max(x0, 0), 31), x1c = min(max(x0 + 1, 0), 31);
        float v00 = sp_row[0][x0c], v01 = sp_row[0][x1c];
        float v10 = sp_row[1][x0c], v11 = sp_row[1][x1c];
        float v0 = v00 + tx * (v01 - v00);
        float v1 = v10 + tx * (v11 - v10);
        pix[(size_t)n * 262144 + (size_t)y * 512 + x] = v0 + ty * (v1 - v0);
    }
}

extern "C" void kernel_launch(void* const* d_in, const int* in_sizes, int n_in,
                              void* d_out, int out_size, void* d_ws, size_t ws_size,
                              hipStream_t stream) {
    const float* feats = (const float*)d_in[0];           // [4,1024,128] f32
    const float* nfeats = (const float*)d_in[1];          // [8,1024,128] f32
    const float* mask = (const float*)d_in[2];            // [4,1024] f32
    float* out = (float*)d_out;                           // [4] scores + [4,512,512]

    unsigned short* fb = (unsigned short*)d_ws;                         // 1 MB
    unsigned short* gb = fb + 4096 * 128;                               // 2 MB
    float* sp_part = (float*)((char*)d_ws + 3u * 1024u * 1024u);        // 1 MB

    knorm<<<3072, 256, 0, stream>>>(feats, nfeats, fb, gb);
    kscore<<<dim3(8, 64, 2), 256, 0, stream>>>(fb, gb, sp_part);
    kfinal<<<dim3(65, 4), 256, 0, stream>>>(sp_part, mask, out);
}

// Round 8
// 31.054 us; speedup vs baseline: 1.4018x; 1.4018x over previous
//
#include <hip/hip_runtime.h>

typedef __attribute__((ext_vector_type(8))) short short8;
typedef __attribute__((ext_vector_type(4))) float f32x4;
typedef __attribute__((ext_vector_type(4))) unsigned int u32x4;

static __device__ inline unsigned short f2bf(float x) {
    unsigned int u = __float_as_uint(x);
    u = (u + 0x7FFFu + ((u >> 16) & 1u)) >> 16;
    return (unsigned short)u;
}

// ---------------- Kernel 1: L2-normalize rows, cast to bf16 ----------------
__global__ __launch_bounds__(256) void knorm(const float* __restrict__ feats,
                                             const float* __restrict__ nfeats,
                                             unsigned short* __restrict__ fb,
                                             unsigned short* __restrict__ gb) {
    int row = blockIdx.x * 4 + (threadIdx.x >> 6);
    int lane = threadIdx.x & 63;
    const float* src;
    unsigned short* dst;
    if (row < 4096) { src = feats + row * 128;           dst = fb + row * 128; }
    else            { src = nfeats + (row - 4096) * 128; dst = gb + (row - 4096) * 128; }
    float2 v = ((const float2*)src)[lane];
    float ss = v.x * v.x + v.y * v.y;
    #pragma unroll
    for (int d = 32; d; d >>= 1) ss += __shfl_xor(ss, d);
    float inv = 1.0f / sqrtf(ss);
    ushort2 o;
    o.x = f2bf(v.x * inv);
    o.y = f2bf(v.y * inv);
    ((ushort2*)dst)[lane] = o;
}

// ---------------- Kernel 2: partial max_q dot(f[p], g[q]) via MFMA ----------
// grid (8 m, 32 = ptile*2+qh), 512 thr = 8 waves.  Block = 256 p x 512 q.
// grid.x = m = 8 pins each m's gb slice to one XCD (linear%8 round-robin).
// REG-STAGED LDS double-buffer (no global_load_lds: that path streams from
// L3/HBM every time — R3 counters: FETCH==WRITE==staging volume).  Plain
// global loads allocate in L2 -> staging reads hit per-XCD L2 after 1st touch.
// One barrier per phase; compiler inserts counted vmcnt for the ds_write dep.
__global__ __launch_bounds__(512, 2) void kscore(const unsigned short* __restrict__ fb,
                                                 const unsigned short* __restrict__ gb,
                                                 float* __restrict__ sp_part) {
    __shared__ char gtile[2][8192];          // 2 x 8KB, XOR-swizzled image
    const int tid = threadIdx.x;
    const int lane = tid & 63;
    const int wave = tid >> 6;               // 0..7
    const int wp = wave >> 1, wqt = wave & 1;
    const int l15 = lane & 15, lhi = lane >> 4;
    const int m = blockIdx.x;
    const int ptile = blockIdx.y >> 1, qh = blockIdx.y & 1;
    const int rowbase = ptile * 256 + wp * 64;   // global f row in [0,4096)

    const unsigned short* gBase = gb + ((size_t)m * 1024 + qh * 512) * 128;

    // per-thread staging addresses: LINEAR global read (fully coalesced),
    // swizzle applied on the ds_write address; LDS image = (r*256+s*16)^((r&7)<<4)
    const int sr = tid >> 4, sc = tid & 15;      // row 0..31, 16B-col 0..15
    const unsigned short* gsrc = gBase + (size_t)sr * 128 + sc * 8;
    const int wofs = (sr * 256 + sc * 16) ^ ((sr & 7) << 4);

    // A fragments: 4 p-groups x 4 k-groups (64 VGPR), persistent
    short8 a[4][4];
    #pragma unroll
    for (int pg = 0; pg < 4; pg++) {
        const unsigned short* arow = fb + (size_t)(rowbase + pg * 16 + l15) * 128;
        #pragma unroll
        for (int kk = 0; kk < 4; kk++)
            a[pg][kk] = *(const short8*)(arow + kk * 32 + lhi * 8);
    }

    f32x4 mx[4];
    #pragma unroll
    for (int pg = 0; pg < 4; pg++)
        #pragma unroll
        for (int i = 0; i < 4; i++) mx[pg][i] = -1e30f;

    // prologue: tile0 -> L0; tile1 load left in flight
    u32x4 st0 = *(const u32x4*)(gsrc);
    *(u32x4*)(gtile[0] + wofs) = st0;            // compiler waits vmcnt for st0 only
    u32x4 stn = *(const u32x4*)(gsrc + 32 * 128);
    asm volatile("s_waitcnt lgkmcnt(0)" ::: "memory");
    __builtin_amdgcn_s_barrier();

    #pragma unroll
    for (int t = 0; t < 16; t++) {
        __builtin_amdgcn_sched_barrier(0);
        // issue tile t+2 global load (stays in flight across this phase)
        u32x4 stnn;
        if (t < 14) stnn = *(const u32x4*)(gsrc + (size_t)(t + 2) * 32 * 128);
        // write tile t+1 into the buffer consumed last phase (safe post-barrier)
        if (t < 15) *(u32x4*)(gtile[(t + 1) & 1] + wofs) = stn;
        // compute tile t from L[t&1]
        const char* tp = gtile[t & 1];
        const int r = wqt * 16 + l15;
        const int rowoff = r * 256;
        const int swz = (r & 7) << 4;
        f32x4 acc[4];
        #pragma unroll
        for (int pg = 0; pg < 4; pg++)
            #pragma unroll
            for (int i = 0; i < 4; i++) acc[pg][i] = 0.f;
        #pragma unroll
        for (int kk = 0; kk < 4; kk++) {
            short8 b = *(const short8*)(tp + ((rowoff + kk * 64 + lhi * 16) ^ swz));
            #pragma unroll
            for (int pg = 0; pg < 4; pg++)
                acc[pg] = __builtin_amdgcn_mfma_f32_16x16x32_bf16(a[pg][kk], b, acc[pg], 0, 0, 0);
        }
        #pragma unroll
        for (int pg = 0; pg < 4; pg++)
            #pragma unroll
            for (int i = 0; i < 4; i++) mx[pg][i] = fmaxf(mx[pg][i], acc[pg][i]);
        if (t < 14) stn = stnn;
        asm volatile("s_waitcnt lgkmcnt(0)" ::: "memory");
        __builtin_amdgcn_s_barrier();
    }

    // reduce max over the 16 q-columns (C/D col = lane&15)
    #pragma unroll
    for (int pg = 0; pg < 4; pg++)
        #pragma unroll
        for (int i = 0; i < 4; i++) {
            float v = mx[pg][i];
            v = fmaxf(v, __shfl_xor(v, 1));
            v = fmaxf(v, __shfl_xor(v, 2));
            v = fmaxf(v, __shfl_xor(v, 4));
            v = fmaxf(v, __shfl_xor(v, 8));
            mx[pg][i] = v;
        }
    if (l15 == 0) {
        const int slot = qh * 2 + wqt;      // 4 disjoint q-partials per (n,m)
        #pragma unroll
        for (int pg = 0; pg < 4; pg++)
            #pragma unroll
            for (int i = 0; i < 4; i++) {
                int row = rowbase + pg * 16 + lhi * 4 + i;   // [0,4096)
                int n = row >> 10, p = row & 1023;
                sp_part[((size_t)(n * 8 + m) * 4 + slot) * 1024 + p] = mx[pg][i];
            }
    }
}

// --------- Kernel 3: fused fold + scores + bilinear upsample ---------------
// grid (65, 4): bx<64 -> 8-row output band; bx==64 -> scores[n]
__global__ __launch_bounds__(256) void kfinal(const float* __restrict__ sp_part,
                                              const float* __restrict__ mask,
                                              float* __restrict__ out) {
    const int n = blockIdx.y;
    const int bx = blockIdx.x;
    const int t = threadIdx.x;
    float* pix = out + 4;

    if (bx == 64) {  // ---- scores[n] = mean_m max_p dist ----
        __shared__ float smax[4];
        float acc = 0.f;
        for (int m = 0; m < 8; m++) {
            const float* base = sp_part + (size_t)(n * 8 + m) * 4 * 1024;
            float lm = -1e30f;
            #pragma unroll
            for (int i = 0; i < 4; i++) {
                int p = i * 256 + t;
                float dot = fmaxf(fmaxf(base[p], base[1024 + p]),
                                  fmaxf(base[2048 + p], base[3072 + p]));
                float d = sqrtf(fmaxf(2.0f - 2.0f * dot, 0.0f)) * 0.5f * mask[n * 1024 + p];
                lm = fmaxf(lm, d);
            }
            #pragma unroll
            for (int d = 32; d; d >>= 1) lm = fmaxf(lm, __shfl_xor(lm, d));
            if ((t & 63) == 0) smax[t >> 6] = lm;
            __syncthreads();
            if (t == 0) acc += fmaxf(fmaxf(smax[0], smax[1]), fmaxf(smax[2], smax[3]));
            __syncthreads();
        }
        if (t == 0) out[n] = acc * 0.125f;
        return;
    }

    // ---- output band: rows [bx*8, bx*8+8); needs 2 consecutive patch rows ----
    __shared__ float sp_row[2][32];
    const int band = bx * 8;
    const int pr_lo = (int)floorf((band + 0.5f) * 0.0625f - 0.5f);
    const int row0 = min(max(pr_lo, 0), 31);
    const int row1 = min(max(pr_lo + 1, 0), 31);
    {
        int v = t >> 2, sub = t & 3;          // 64 values x 4 threads
        int vr = v >> 5, vc = v & 31;
        int p = (vr ? row1 : row0) * 32 + vc;
        float sum = 0.f;
        #pragma unroll
        for (int mi = 0; mi < 2; mi++) {
            int m = sub * 2 + mi;
            const float* base = sp_part + (size_t)(n * 8 + m) * 4 * 1024 + p;
            float dot = fmaxf(fmaxf(base[0], base[1024]),
                              fmaxf(base[2048], base[3072]));
            sum += sqrtf(fmaxf(2.0f - 2.0f * dot, 0.0f)) * 0.5f;
        }
        sum *= mask[n * 1024 + p];
        sum += __shfl_xor(sum, 1);
        sum += __shfl_xor(sum, 2);
        if (sub == 0) sp_row[vr][vc] = sum * 0.125f;
    }
    __syncthreads();
    #pragma unroll
    for (int i = 0; i < 16; i++) {
        int idx = i * 256 + t;
        int yl = idx >> 9, x = idx & 511;
        int y = band + yl;
        float fy = (y + 0.5f) * 0.0625f - 0.5f;
        float ty = fy - (float)pr_lo;          // rows {pr_lo, pr_lo+1}; clamped dup at edges
        float fx = (x + 0.5f) * 0.0625f - 0.5f;
        float xf = floorf(fx);
        float tx = fx - xf;
        int x0 = (int)xf;
        int x0c = min(max(x0, 0), 31), x1c = min(max(x0 + 1, 0), 31);
        float v00 = sp_row[0][x0c], v01 = sp_row[0][x1c];
        float v10 = sp_row[1][x0c], v11 = sp_row[1][x1c];
        float v0 = v00 + tx * (v01 - v00);
        float v1 = v10 + tx * (v11 - v10);
        pix[(size_t)n * 262144 + (size_t)y * 512 + x] = v0 + ty * (v1 - v0);
    }
}

extern "C" void kernel_launch(void* const* d_in, const int* in_sizes, int n_in,
                              void* d_out, int out_size, void* d_ws, size_t ws_size,
                              hipStream_t stream) {
    const float* feats = (const float*)d_in[0];           // [4,1024,128] f32
    const float* nfeats = (const float*)d_in[1];          // [8,1024,128] f32
    const float* mask = (const float*)d_in[2];            // [4,1024] f32
    float* out = (float*)d_out;                           // [4] scores + [4,512,512]

    unsigned short* fb = (unsigned short*)d_ws;                         // 1 MB
    unsigned short* gb = fb + 4096 * 128;                               // 2 MB
    float* sp_part = (float*)((char*)d_ws + 3u * 1024u * 1024u);        // 512 KB

    knorm<<<3072, 256, 0, stream>>>(feats, nfeats, fb, gb);
    kscore<<<dim3(8, 32), 512, 0, stream>>>(fb, gb, sp_part);
    kfinal<<<dim3(65, 4), 256, 0, stream>>>(sp_part, mask, out);
}

// Round 9
// 30.086 us; speedup vs baseline: 1.4469x; 1.0322x over previous
//
#include <hip/hip_runtime.h>

typedef __attribute__((ext_vector_type(8))) short short8;
typedef __attribute__((ext_vector_type(4))) float f32x4;
typedef __attribute__((ext_vector_type(4))) unsigned int u32x4;

static __device__ inline unsigned short f2bf(float x) {
    unsigned int u = __float_as_uint(x);
    u = (u + 0x7FFFu + ((u >> 16) & 1u)) >> 16;
    return (unsigned short)u;
}

// ---------------- Kernel 1: L2-normalize rows, cast to bf16 ----------------
__global__ __launch_bounds__(256) void knorm(const float* __restrict__ feats,
                                             const float* __restrict__ nfeats,
                                             unsigned short* __restrict__ fb,
                                             unsigned short* __restrict__ gb) {
    int row = blockIdx.x * 4 + (threadIdx.x >> 6);
    int lane = threadIdx.x & 63;
    const float* src;
    unsigned short* dst;
    if (row < 4096) { src = feats + row * 128;           dst = fb + row * 128; }
    else            { src = nfeats + (row - 4096) * 128; dst = gb + (row - 4096) * 128; }
    float2 v = ((const float2*)src)[lane];
    float ss = v.x * v.x + v.y * v.y;
    #pragma unroll
    for (int d = 32; d; d >>= 1) ss += __shfl_xor(ss, d);
    float inv = 1.0f / sqrtf(ss);
    ushort2 o;
    o.x = f2bf(v.x * inv);
    o.y = f2bf(v.y * inv);
    ((ushort2*)dst)[lane] = o;
}

// ---------------- Kernel 2: partial max_q dot(f[p], g[q]) via MFMA ----------
// grid (8 m, 64 = ptile*4+qq), 256 thr = 4 waves; block = 256p x 256q.
// 512 blocks = 2 INDEPENDENT blocks/CU: separate barrier domains overlap each
// other's staging stalls (the lockstep-1-block/CU structure was the 4-5x gap).
// grid.x = m = 8 pins each m's gb slice to one XCD (linear%8 round-robin).
// Reg-staged LDS double-buffer, one barrier per phase, 8 phases of 32 q-rows.
__global__ __launch_bounds__(256, 2) void kscore(const unsigned short* __restrict__ fb,
                                                 const unsigned short* __restrict__ gb,
                                                 float* __restrict__ sp_part) {
    __shared__ char gtile[2][8192];          // 2 x 8KB, XOR-swizzled image
    const int tid = threadIdx.x;
    const int lane = tid & 63;
    const int wave = tid >> 6;               // 0..3 = p-subtile
    const int l15 = lane & 15, lhi = lane >> 4;
    const int m = blockIdx.x;
    const int ptile = blockIdx.y >> 2, qq = blockIdx.y & 3;
    const int rowbase = ptile * 256 + wave * 64;   // global f row in [0,4096)

    const unsigned short* gBase = gb + ((size_t)m * 1024 + qq * 256) * 128;

    // staging: 2 granules (16B) per thread; LINEAR global read, swizzle on the
    // ds_write address; LDS image = (r*256+s*16)^((r&7)<<4), r=0..31, s=0..15
    const int r0 = tid >> 4, s0 = tid & 15;
    const int r1 = r0 + 16;
    const unsigned short* gsrc0 = gBase + (size_t)r0 * 128 + s0 * 8;
    const unsigned short* gsrc1 = gBase + (size_t)r1 * 128 + s0 * 8;
    const int wofs0 = (r0 * 256 + s0 * 16) ^ ((r0 & 7) << 4);
    const int wofs1 = (r1 * 256 + s0 * 16) ^ ((r1 & 7) << 4);

    // A fragments: 4 p-groups x 4 k-groups (64 VGPR), persistent
    short8 a[4][4];
    #pragma unroll
    for (int pg = 0; pg < 4; pg++) {
        const unsigned short* arow = fb + (size_t)(rowbase + pg * 16 + l15) * 128;
        #pragma unroll
        for (int kk = 0; kk < 4; kk++)
            a[pg][kk] = *(const short8*)(arow + kk * 32 + lhi * 8);
    }

    f32x4 mx[4];
    #pragma unroll
    for (int pg = 0; pg < 4; pg++)
        #pragma unroll
        for (int i = 0; i < 4; i++) mx[pg][i] = -1e30f;

    // prologue: tile0 -> L0; tile1 loads left in flight
    u32x4 t0a = *(const u32x4*)(gsrc0);
    u32x4 t0b = *(const u32x4*)(gsrc1);
    *(u32x4*)(gtile[0] + wofs0) = t0a;
    *(u32x4*)(gtile[0] + wofs1) = t0b;
    u32x4 stna = *(const u32x4*)(gsrc0 + 32 * 128);
    u32x4 stnb = *(const u32x4*)(gsrc1 + 32 * 128);
    asm volatile("s_waitcnt lgkmcnt(0)" ::: "memory");
    __builtin_amdgcn_s_barrier();

    #pragma unroll
    for (int t = 0; t < 8; t++) {
        __builtin_amdgcn_sched_barrier(0);
        // issue tile t+2 loads (stay in flight across this phase)
        u32x4 s2a, s2b;
        if (t < 6) {
            s2a = *(const u32x4*)(gsrc0 + (size_t)(t + 2) * 32 * 128);
            s2b = *(const u32x4*)(gsrc1 + (size_t)(t + 2) * 32 * 128);
        }
        // write tile t+1 into the buffer consumed last phase (safe post-barrier)
        if (t < 7) {
            *(u32x4*)(gtile[(t + 1) & 1] + wofs0) = stna;
            *(u32x4*)(gtile[(t + 1) & 1] + wofs1) = stnb;
        }
        // compute tile t: 2 q-subtiles x 4 kk x 4 pg = 32 MFMA
        const char* tp = gtile[t & 1];
        #pragma unroll
        for (int qt = 0; qt < 2; qt++) {
            const int r = qt * 16 + l15;
            const int rowoff = r * 256;
            const int swz = (r & 7) << 4;
            f32x4 acc[4];
            #pragma unroll
            for (int pg = 0; pg < 4; pg++)
                #pragma unroll
                for (int i = 0; i < 4; i++) acc[pg][i] = 0.f;
            #pragma unroll
            for (int kk = 0; kk < 4; kk++) {
                short8 b = *(const short8*)(tp + ((rowoff + kk * 64 + lhi * 16) ^ swz));
                #pragma unroll
                for (int pg = 0; pg < 4; pg++)
                    acc[pg] = __builtin_amdgcn_mfma_f32_16x16x32_bf16(a[pg][kk], b, acc[pg], 0, 0, 0);
            }
            #pragma unroll
            for (int pg = 0; pg < 4; pg++)
                #pragma unroll
                for (int i = 0; i < 4; i++) mx[pg][i] = fmaxf(mx[pg][i], acc[pg][i]);
        }
        if (t < 6) { stna = s2a; stnb = s2b; }
        asm volatile("s_waitcnt lgkmcnt(0)" ::: "memory");
        __builtin_amdgcn_s_barrier();
    }

    // reduce max over the 16 q-columns (C/D col = lane&15)
    #pragma unroll
    for (int pg = 0; pg < 4; pg++)
        #pragma unroll
        for (int i = 0; i < 4; i++) {
            float v = mx[pg][i];
            v = fmaxf(v, __shfl_xor(v, 1));
            v = fmaxf(v, __shfl_xor(v, 2));
            v = fmaxf(v, __shfl_xor(v, 4));
            v = fmaxf(v, __shfl_xor(v, 8));
            mx[pg][i] = v;
        }
    if (l15 == 0) {
        #pragma unroll
        for (int pg = 0; pg < 4; pg++)
            #pragma unroll
            for (int i = 0; i < 4; i++) {
                int row = rowbase + pg * 16 + lhi * 4 + i;   // [0,4096)
                int n = row >> 10, p = row & 1023;
                sp_part[((size_t)(n * 8 + m) * 4 + qq) * 1024 + p] = mx[pg][i];
            }
    }
}

// --------- Kernel 3: fused fold + scores + bilinear upsample ---------------
// grid (65, 4): bx<64 -> 8-row output band; bx==64 -> scores[n]
__global__ __launch_bounds__(256) void kfinal(const float* __restrict__ sp_part,
                                              const float* __restrict__ mask,
                                              float* __restrict__ out) {
    const int n = blockIdx.y;
    const int bx = blockIdx.x;
    const int t = threadIdx.x;
    float* pix = out + 4;

    if (bx == 64) {  // ---- scores[n] = mean_m max_p dist ----
        __shared__ float smax[4];
        float acc = 0.f;
        for (int m = 0; m < 8; m++) {
            const float* base = sp_part + (size_t)(n * 8 + m) * 4 * 1024;
            float lm = -1e30f;
            #pragma unroll
            for (int i = 0; i < 4; i++) {
                int p = i * 256 + t;
                float dot = fmaxf(fmaxf(base[p], base[1024 + p]),
                                  fmaxf(base[2048 + p], base[3072 + p]));
                float d = sqrtf(fmaxf(2.0f - 2.0f * dot, 0.0f)) * 0.5f * mask[n * 1024 + p];
                lm = fmaxf(lm, d);
            }
            #pragma unroll
            for (int d = 32; d; d >>= 1) lm = fmaxf(lm, __shfl_xor(lm, d));
            if ((t & 63) == 0) smax[t >> 6] = lm;
            __syncthreads();
            if (t == 0) acc += fmaxf(fmaxf(smax[0], smax[1]), fmaxf(smax[2], smax[3]));
            __syncthreads();
        }
        if (t == 0) out[n] = acc * 0.125f;
        return;
    }

    // ---- output band: rows [bx*8, bx*8+8); needs 2 consecutive patch rows ----
    __shared__ float sp_row[2][32];
    const int band = bx * 8;
    const int pr_lo = (int)floorf((band + 0.5f) * 0.0625f - 0.5f);
    const int row0 = min(max(pr_lo, 0), 31);
    const int row1 = min(max(pr_lo + 1, 0), 31);
    {
        int v = t >> 2, sub = t & 3;          // 64 values x 4 threads
        int vr = v >> 5, vc = v & 31;
        int p = (vr ? row1 : row0) * 32 + vc;
        float sum = 0.f;
        #pragma unroll
        for (int mi = 0; mi < 2; mi++) {
            int m = sub * 2 + mi;
            const float* base = sp_part + (size_t)(n * 8 + m) * 4 * 1024 + p;
            float dot = fmaxf(fmaxf(base[0], base[1024]),
                              fmaxf(base[2048], base[3072]));
            sum += sqrtf(fmaxf(2.0f - 2.0f * dot, 0.0f)) * 0.5f;
        }
        sum *= mask[n * 1024 + p];
        sum += __shfl_xor(sum, 1);
        sum += __shfl_xor(sum, 2);
        if (sub == 0) sp_row[vr][vc] = sum * 0.125f;
    }
    __syncthreads();
    #pragma unroll
    for (int i = 0; i < 16; i++) {
        int idx = i * 256 + t;
        int yl = idx >> 9, x = idx & 511;
        int y = band + yl;
        float fy = (y + 0.5f) * 0.0625f - 0.5f;
        float ty = fy - (float)pr_lo;          // rows {pr_lo, pr_lo+1}; clamped dup at edges
        float fx = (x + 0.5f) * 0.0625f - 0.5f;
        float xf = floorf(fx);
        float tx = fx - xf;
        int x0 = (int)xf;
        int x0c = min(max(x0, 0), 31), x1c = min(max(x0 + 1, 0), 31);
        float v00 = sp_row[0][x0c], v01 = sp_row[0][x1c];
        float v10 = sp_row[1][x0c], v11 = sp_row[1][x1c];
        float v0 = v00 + tx * (v01 - v00);
        float v1 = v10 + tx * (v11 - v10);
        pix[(size_t)n * 262144 + (size_t)y * 512 + x] = v0 + ty * (v1 - v0);
    }
}

extern "C" void kernel_launch(void* const* d_in, const int* in_sizes, int n_in,
                              void* d_out, int out_size, void* d_ws, size_t ws_size,
                              hipStream_t stream) {
    const float* feats = (const float*)d_in[0];           // [4,1024,128] f32
    const float* nfeats = (const float*)d_in[1];          // [8,1024,128] f32
    const float* mask = (const float*)d_in[2];            // [4,1024] f32
    float* out = (float*)d_out;                           // [4] scores + [4,512,512]

    unsigned short* fb = (unsigned short*)d_ws;                         // 1 MB
    unsigned short* gb = fb + 4096 * 128;                               // 2 MB
    float* sp_part = (float*)((char*)d_ws + 3u * 1024u * 1024u);        // 512 KB

    knorm<<<3072, 256, 0, stream>>>(feats, nfeats, fb, gb);
    kscore<<<dim3(8, 64), 256, 0, stream>>>(fb, gb, sp_part);
    kfinal<<<dim3(65, 4), 256, 0, stream>>>(sp_part, mask, out);
}